// Round 1
// baseline (1683.882 us; speedup 1.0000x reference)
//
#include <hip/hip_runtime.h>
#include <hip/hip_bf16.h>
#include <math.h>

// Problem dims
#define TI 128
#define NB 8
#define TO 32
#define TT 33      // TO+1
#define D 512
#define NH 8
#define HD 64
#define FF 2048
#define V 2000
#define NL 6
#define NTOK (TT*NB)   // 264 tokens, row = t*NB + n
#define MJ (NB*TI*TT)  // 33792 joiner rows, row = (n*TI+ti)*TT + t
#define GRID 256       // resident-grid size for the fused decoder

typedef __attribute__((ext_vector_type(4))) float  f4;
typedef __attribute__((ext_vector_type(8))) short  shortx8;
typedef unsigned short u16;

// weight plane element offsets inside Wh/Wl
static constexpr size_t QO = 0;              // + l*786432   (1536x512)
static constexpr size_t OO = 4718592;        // + l*262144   (512x512)
static constexpr size_t F1 = 6291456;        // + l*1048576  (2048x512)
static constexpr size_t F2 = 12582912;       // + l*1048576  (512x2048)
static constexpr size_t EW = 18874368;       // 512x512

__device__ __forceinline__ u16 f2bf(float f) {
    unsigned u = __float_as_uint(f);
    unsigned r = (u + 0x7fffu + ((u >> 16) & 1u)) >> 16;
    return (u16)r;
}
__device__ __forceinline__ float bf2f(u16 h) {
    return __uint_as_float(((unsigned)h) << 16);
}
__device__ __forceinline__ float wsum(float v) {
#pragma unroll
    for (int off = 32; off; off >>= 1) v += __shfl_xor(v, off, 64);
    return v;
}
__device__ __forceinline__ float wmax(float v) {
#pragma unroll
    for (int off = 32; off; off >>= 1) v = fmaxf(v, __shfl_xor(v, off, 64));
    return v;
}
__device__ __forceinline__ f4 mfma16(shortx8 a, shortx8 b, f4 c) {
    return __builtin_amdgcn_mfma_f32_16x16x32_bf16(a, b, c, 0, 0, 0);
}
__device__ __forceinline__ void async16(const void* g, void* l) {
    __builtin_amdgcn_global_load_lds(
        (const __attribute__((address_space(1))) unsigned int*)g,
        (__attribute__((address_space(3))) unsigned int*)l, 16, 0, 0);
}

// Resident-grid barrier: monotonic counter, AGENT-scope atomics.
// Correct because grid == 256 blocks <= 256 CUs and the kernel fits
// >=1 block/CU (32 KiB LDS, __launch_bounds__(256,1)) -> all blocks
// co-resident, no scheduling deadlock. __threadfence() gives the
// cross-XCD L2 writeback/invalidate (per-XCD L2s are not coherent).
__device__ __forceinline__ void grid_sync(unsigned* bar) {
    __syncthreads();
    if (threadIdx.x == 0) {
        __threadfence();  // release: flush this XCD's dirty L2 lines
        unsigned my = __hip_atomic_fetch_add(bar, 1u, __ATOMIC_RELAXED,
                                             __HIP_MEMORY_SCOPE_AGENT);
        unsigned target = (my / (unsigned)GRID + 1u) * (unsigned)GRID;
        while (__hip_atomic_load(bar, __ATOMIC_RELAXED,
                                 __HIP_MEMORY_SCOPE_AGENT) < target)
            __builtin_amdgcn_s_sleep(4);
        __threadfence();  // acquire: invalidate stale L1/L2 lines
    }
    __syncthreads();
}

// ---------------- fused pre-pass: weight split + enc split + embed --------
// blocks [0,18688): convert qkv/o/ff1/ff2/enc weights fp32 -> bf16 hi/lo
// blocks [18688,19200): convert enc_out
// blocks [19200,19728): embedding + positional encoding
__global__ __launch_bounds__(256) void fused_convert(
    const float* __restrict__ qw, const float* __restrict__ ow,
    const float* __restrict__ f1w, const float* __restrict__ f2w,
    const float* __restrict__ ew, u16* __restrict__ Wh, u16* __restrict__ Wl,
    const float* __restrict__ enc_out, u16* __restrict__ eh, u16* __restrict__ el,
    const float* __restrict__ emb, const int* __restrict__ tgt_pad,
    const int* __restrict__ sos, float* __restrict__ x,
    u16* __restrict__ xh, u16* __restrict__ xl, unsigned* __restrict__ bar)
{
    const int bid = blockIdx.x, tid = threadIdx.x;
    if (bid == 0 && tid == 0)
        __hip_atomic_store(bar, 0u, __ATOMIC_RELEASE, __HIP_MEMORY_SCOPE_AGENT);
    if (bid < 18688) {
        int i4 = bid * 256 + tid;   // 4784128 total f4 units
        const float* src; int loc;
        if (i4 < 1179648)      { src = qw;  loc = i4; }
        else if (i4 < 1572864) { src = ow;  loc = i4 - 1179648; }
        else if (i4 < 3145728) { src = f1w; loc = i4 - 1572864; }
        else if (i4 < 4718592) { src = f2w; loc = i4 - 3145728; }
        else                   { src = ew;  loc = i4 - 4718592; }
        f4 v = *(const f4*)(src + (size_t)loc * 4);
        ushort4 h, l;
        h.x = f2bf(v[0]); l.x = f2bf(v[0] - bf2f(h.x));
        h.y = f2bf(v[1]); l.y = f2bf(v[1] - bf2f(h.y));
        h.z = f2bf(v[2]); l.z = f2bf(v[2] - bf2f(h.z));
        h.w = f2bf(v[3]); l.w = f2bf(v[3] - bf2f(h.w));
        *(ushort4*)(Wh + (size_t)i4 * 4) = h;
        *(ushort4*)(Wl + (size_t)i4 * 4) = l;
    } else if (bid < 19200) {
        int i = (bid - 18688) * 256 + tid;   // 131072 f4 units
        f4 v = *(const f4*)(enc_out + (size_t)i * 4);
        ushort4 h, l;
        h.x = f2bf(v[0]); l.x = f2bf(v[0] - bf2f(h.x));
        h.y = f2bf(v[1]); l.y = f2bf(v[1] - bf2f(h.y));
        h.z = f2bf(v[2]); l.z = f2bf(v[2] - bf2f(h.z));
        h.w = f2bf(v[3]); l.w = f2bf(v[3] - bf2f(h.w));
        *(ushort4*)(eh + (size_t)i * 4) = h;
        *(ushort4*)(el + (size_t)i * 4) = l;
    } else {
        int idx = (bid - 19200) * 256 + tid;   // NTOK*D = 135168
        if (idx < NTOK * D) {
            int d = idx & (D - 1);
            int row = idx >> 9;
            int t = row >> 3, n = row & 7;
            int tok = (t == 0) ? *sos : tgt_pad[n * TO + t - 1];
            float freq = __expf((float)(d & ~1) * (-0.017988946039015984f));
            float ang = (float)t * freq;
            float pe = (d & 1) ? cosf(ang) : sinf(ang);
            float v = emb[tok * D + d] * 22.627416997969522f + pe;
            x[idx] = v;
            u16 h = f2bf(v);
            xh[idx] = h;
            xl[idx] = f2bf(v - bf2f(h));
        }
    }
}

// ---------------- bf16 hi/lo GEMM tile body (device fn) -------------------
// 64x64 tile, BK=64, global_load_lds width-16 staging, 3-product split MFMA.
// MODE 0: fp32 out + bias. MODE 1: fp32 split-K partial (slice zz, offset
// zz*M*ldc, k-base zz*ksteps*64), no bias. MODE 2: bf16 hi/lo + bias + relu.
template<int MODE>
__device__ void gemm_tile(
    u16 (*ls)[64 * 64], int mt, int nt, int zz,
    const u16* __restrict__ Ah, const u16* __restrict__ Al, int lda,
    const u16* __restrict__ Bh, const u16* __restrict__ Bl, int ldb,
    const float* __restrict__ bias,
    float* __restrict__ C, u16* __restrict__ Ch, u16* __restrict__ Cl,
    int M, int ldc, int ksteps)
{
    const int tid = threadIdx.x, lane = tid & 63, w = tid >> 6;
    const int wr = (w >> 1) * 32, wc = (w & 1) * 32;
    const int m0 = mt * 64, n0 = nt * 64;
    const int qd = lane >> 4, mm = lane & 15;
    const int kb = (MODE == 1) ? zz * ksteps * 64 : 0;
    f4 acc[2][2] = {};
    const u16* Ab  = Ah + (size_t)m0 * lda + kb;
    const u16* Alb = Al + (size_t)m0 * lda + kb;
    const u16* Bb  = Bh + (size_t)n0 * ldb + kb;
    const u16* Blb = Bl + (size_t)n0 * ldb + kb;

    for (int it = 0; it < ksteps; ++it) {
        int k0 = it * 64;
        __syncthreads();
#pragma unroll
        for (int i = 0; i < 2; ++i) {
            int idx = tid + i * 256;
            int row = idx >> 3, c8 = (idx & 7) * 8;
            async16(Ab  + (size_t)row * lda + k0 + c8, &ls[0][idx * 8]);
            async16(Alb + (size_t)row * lda + k0 + c8, &ls[1][idx * 8]);
            async16(Bb  + (size_t)row * ldb + k0 + c8, &ls[2][idx * 8]);
            async16(Blb + (size_t)row * ldb + k0 + c8, &ls[3][idx * 8]);
        }
        __syncthreads();
#pragma unroll
        for (int kk = 0; kk < 2; ++kk) {
            shortx8 aH[2], aL[2], bH[2], bL[2];
#pragma unroll
            for (int rt = 0; rt < 2; ++rt) {
                int row = wr + rt * 16 + mm;
                aH[rt] = *(const shortx8*)&ls[0][row * 64 + kk * 32 + qd * 8];
                aL[rt] = *(const shortx8*)&ls[1][row * 64 + kk * 32 + qd * 8];
                int col = wc + rt * 16 + mm;
                bH[rt] = *(const shortx8*)&ls[2][col * 64 + kk * 32 + qd * 8];
                bL[rt] = *(const shortx8*)&ls[3][col * 64 + kk * 32 + qd * 8];
            }
#pragma unroll
            for (int rt = 0; rt < 2; ++rt)
#pragma unroll
                for (int ct = 0; ct < 2; ++ct) {
                    acc[rt][ct] = mfma16(aH[rt], bH[ct], acc[rt][ct]);
                    acc[rt][ct] = mfma16(aH[rt], bL[ct], acc[rt][ct]);
                    acc[rt][ct] = mfma16(aL[rt], bH[ct], acc[rt][ct]);
                }
        }
    }
    float* Cz = C;
    if (MODE == 1) Cz = C + (size_t)zz * (size_t)M * ldc;
#pragma unroll
    for (int rt = 0; rt < 2; ++rt)
#pragma unroll
        for (int ct = 0; ct < 2; ++ct)
#pragma unroll
            for (int reg = 0; reg < 4; ++reg) {
                int grow = m0 + wr + rt * 16 + qd * 4 + reg;
                int gcol = n0 + wc + ct * 16 + mm;
                if (grow < M) {
                    float v = acc[rt][ct][reg];
                    if (MODE != 1) v += bias[gcol];
                    if (MODE == 2) {
                        v = fmaxf(v, 0.f);
                        u16 h = f2bf(v);
                        Ch[(size_t)grow * ldc + gcol] = h;
                        Cl[(size_t)grow * ldc + gcol] = f2bf(v - bf2f(h));
                    } else {
                        Cz[(size_t)grow * ldc + gcol] = v;
                    }
                }
            }
}

// ---------------- attention body (one "block slot" per (n,h)) -------------
__device__ void attn_body(u16* lsr, int bid,
                          const float* __restrict__ qkv,
                          const int* __restrict__ tgt_len,
                          u16* __restrict__ oh, u16* __restrict__ ol)
{
    const int n = bid >> 3, h = bid & 7;
    const int tid = threadIdx.x, lane = tid & 63, w = tid >> 6;
    float* sq  = (float*)lsr;          // [t][d]   TT*HD
    float* skT = sq + TT * HD;         // [d][t]   HD*TT
    float* sv  = skT + HD * TT;        // [t][d]   TT*HD
    for (int idx = tid; idx < TT * HD; idx += 256) {
        int t = idx >> 6, d = idx & 63;
        size_t base = (size_t)(t * NB + n) * (3 * D) + h * HD + d;
        sq[idx] = qkv[base] * 0.125f;          // 1/sqrt(64)
        skT[d * TT + t] = qkv[base + D];
        sv[idx] = qkv[base + 2 * D];
    }
    int len = max(tgt_len[n], 1);
    __syncthreads();
    for (int r = w; r < TT; r += 4) {
        bool ok = (lane < TT) && (lane <= r) && (lane < len);
        float s = -INFINITY;
        if (ok) {
            float dot = 0.f;
#pragma unroll 8
            for (int d = 0; d < HD; ++d) dot += sq[r * HD + d] * skT[d * TT + lane];
            s = dot;
        }
        float mx = wmax(s);
        float e = ok ? __expf(s - mx) : 0.f;
        float sum = wsum(e);
        float att = e / sum;
        float o = 0.f;
#pragma unroll
        for (int k = 0; k < TT; ++k) {
            float a = __shfl(att, k, 64);
            o += a * sv[k * HD + lane];
        }
        size_t oi = (size_t)(r * NB + n) * D + h * HD + lane;
        u16 hv = f2bf(o);
        oh[oi] = hv;
        ol[oi] = f2bf(o - bf2f(hv));
    }
}

// ---------------- residual add (+NP partials) + LayerNorm body ------------
template<int NP, int BIAS>
__device__ void add_ln_body(int bid,
    float* __restrict__ x, const float* __restrict__ r,
    const float* __restrict__ bias2,
    const float* __restrict__ s, const float* __restrict__ b,
    u16* __restrict__ xh, u16* __restrict__ xl)
{
    int row = bid * 4 + (threadIdx.x >> 6);
    int lane = threadIdx.x & 63;
    if (row >= NTOK) return;
    float* xr = x + (size_t)row * D;
    f4 v1 = *(const f4*)(xr + lane * 4);
    f4 v2 = *(const f4*)(xr + 256 + lane * 4);
#pragma unroll
    for (int p = 0; p < NP; ++p) {
        const float* rr = r + (size_t)p * (NTOK * D) + (size_t)row * D;
        v1 += *(const f4*)(rr + lane * 4);
        v2 += *(const f4*)(rr + 256 + lane * 4);
    }
    if (BIAS) {
        v1 += *(const f4*)(bias2 + lane * 4);
        v2 += *(const f4*)(bias2 + 256 + lane * 4);
    }
    float sum = 0.f, sq = 0.f;
#pragma unroll
    for (int j = 0; j < 4; ++j) {
        sum += v1[j] + v2[j];
        sq += v1[j] * v1[j] + v2[j] * v2[j];
    }
    sum = wsum(sum); sq = wsum(sq);
    float mean = sum * (1.f / D);
    float var = sq * (1.f / D) - mean * mean;
    float rstd = rsqrtf(var + 1e-5f);
    f4 o1, o2;
    ushort4 h1, l1, h2, l2;
    u16 th, tl;
#pragma unroll
    for (int j = 0; j < 4; ++j) {
        int c1 = lane * 4 + j, c2 = c1 + 256;
        o1[j] = (v1[j] - mean) * rstd * s[c1] + b[c1];
        o2[j] = (v2[j] - mean) * rstd * s[c2] + b[c2];
    }
    th = f2bf(o1[0]); tl = f2bf(o1[0] - bf2f(th)); h1.x = th; l1.x = tl;
    th = f2bf(o1[1]); tl = f2bf(o1[1] - bf2f(th)); h1.y = th; l1.y = tl;
    th = f2bf(o1[2]); tl = f2bf(o1[2] - bf2f(th)); h1.z = th; l1.z = tl;
    th = f2bf(o1[3]); tl = f2bf(o1[3] - bf2f(th)); h1.w = th; l1.w = tl;
    th = f2bf(o2[0]); tl = f2bf(o2[0] - bf2f(th)); h2.x = th; l2.x = tl;
    th = f2bf(o2[1]); tl = f2bf(o2[1] - bf2f(th)); h2.y = th; l2.y = tl;
    th = f2bf(o2[2]); tl = f2bf(o2[2] - bf2f(th)); h2.z = th; l2.z = tl;
    th = f2bf(o2[3]); tl = f2bf(o2[3] - bf2f(th)); h2.w = th; l2.w = tl;
    *(f4*)(xr + lane * 4) = o1;
    *(f4*)(xr + 256 + lane * 4) = o2;
    *(ushort4*)(xh + (size_t)row * D + lane * 4) = h1;
    *(ushort4*)(xl + (size_t)row * D + lane * 4) = l1;
    *(ushort4*)(xh + (size_t)row * D + 256 + lane * 4) = h2;
    *(ushort4*)(xl + (size_t)row * D + 256 + lane * 4) = l2;
}

// ---------------- fused 6-layer decoder (resident grid, atomic barriers) --
// Stages per layer: qkv(120 tiles [+128 enc tiles @ l=0]) | attn(64) |
// o-proj splitK4(160) | ln1(66) | ff1(160) | ff2 splitK4(160) | ln2(66).
// 41 grid syncs total (last ln2 visibility handled by kernel boundary).
__global__ __launch_bounds__(256, 1) void decoder_coop(
    const u16* __restrict__ Wh, const u16* __restrict__ Wl,
    const float* __restrict__ qkv_b, const float* __restrict__ o_b,
    const float* __restrict__ ln1_s, const float* __restrict__ ln1_b,
    const float* __restrict__ ff1_b, const float* __restrict__ ff2_b,
    const float* __restrict__ ln2_s, const float* __restrict__ ln2_b,
    const float* __restrict__ enc_b, const int* __restrict__ tgt_len,
    float* __restrict__ x, float* __restrict__ qkvb,
    float* __restrict__ part, float* __restrict__ encb,
    u16* __restrict__ xh, u16* __restrict__ xl,
    u16* __restrict__ oh, u16* __restrict__ ol,
    u16* __restrict__ hh, u16* __restrict__ hl,
    const u16* __restrict__ eh, const u16* __restrict__ el,
    unsigned* __restrict__ bar)
{
    __shared__ u16 ls[4][64 * 64];   // 32 KiB, reused as fp32 for attn
    const int bid = blockIdx.x;

    for (int l = 0; l < NL; ++l) {
        const u16* WqH = Wh + QO + (size_t)l * 786432;
        const u16* WqL = Wl + QO + (size_t)l * 786432;
        const u16* WoH = Wh + OO + (size_t)l * 262144;
        const u16* WoL = Wl + OO + (size_t)l * 262144;
        const u16* W1H = Wh + F1 + (size_t)l * 1048576;
        const u16* W1L = Wl + F1 + (size_t)l * 1048576;
        const u16* W2H = Wh + F2 + (size_t)l * 1048576;
        const u16* W2L = Wl + F2 + (size_t)l * 1048576;

        // S1: qkv projection; layer 0 also runs the (independent) enc GEMM
        if (bid < 120) {
            gemm_tile<0>(ls, bid / 24, bid % 24, 0,
                         xh, xl, 512, WqH, WqL, 512,
                         qkv_b + l * 1536, qkvb, nullptr, nullptr,
                         NTOK, 1536, 8);
        } else if (l == 0 && bid < 248) {
            int t = bid - 120;   // 16 row-tiles x 8 col-tiles
            gemm_tile<0>(ls, t >> 3, t & 7, 0,
                         eh, el, 512, Wh + EW, Wl + EW, 512,
                         enc_b, encb, nullptr, nullptr,
                         TI * NB, 512, 8);
        }
        grid_sync(bar);

        // S2: attention
        if (bid < NB * NH) attn_body((u16*)ls, bid, qkvb, tgt_len, oh, ol);
        grid_sync(bar);

        // S3: o-projection, split-K x4 (K=512 -> 4 slices of 128)
        if (bid < 160) {
            int z = bid / 40, r = bid - z * 40;
            gemm_tile<1>(ls, r / 8, r % 8, z,
                         oh, ol, 512, WoH, WoL, 512,
                         nullptr, part, nullptr, nullptr,
                         NTOK, 512, 2);
        }
        grid_sync(bar);

        // S4: x = LN(x + sum(part) + o_b)
        if (bid < 66) add_ln_body<4, 1>(bid, x, part, o_b + l * 512,
                                        ln1_s + l * 512, ln1_b + l * 512, xh, xl);
        grid_sync(bar);

        // S5: ff1 + relu -> bf16 hi/lo
        if (bid < 160) {
            gemm_tile<2>(ls, bid / 32, bid % 32, 0,
                         xh, xl, 512, W1H, W1L, 512,
                         ff1_b + l * 2048, nullptr, hh, hl,
                         NTOK, 2048, 8);
        }
        grid_sync(bar);

        // S6: ff2, split-K x4 (K=2048 -> 4 slices of 512)
        if (bid < 160) {
            int z = bid / 40, r = bid - z * 40;
            gemm_tile<1>(ls, r / 8, r % 8, z,
                         hh, hl, 2048, W2H, W2L, 2048,
                         nullptr, part, nullptr, nullptr,
                         NTOK, 512, 8);
        }
        grid_sync(bar);

        // S7: x = LN(x + sum(part) + ff2_b)
        if (bid < 66) add_ln_body<4, 1>(bid, x, part, ff2_b + l * 512,
                                        ln2_s + l * 512, ln2_b + l * 512, xh, xl);
        if (l < NL - 1) grid_sync(bar);
    }
}

// ---------------- joiner prep: A = bf16(tanh(enc + x)), B = bf16(out_w) ---
// blocks [0,8448): A (MJ*D/8 elems-of-8), blocks [8448,8960): B (2048x512)
__global__ __launch_bounds__(256) void prep_joiner(
    const float* __restrict__ encb, const float* __restrict__ x,
    u16* __restrict__ Aj, const float* __restrict__ out_w, u16* __restrict__ Bj)
{
    const int bid = blockIdx.x;
    if (bid < 8448) {
        int idx = bid * 256 + threadIdx.x;
        int d8 = (idx & 63) << 3;
        int row = idx >> 6;                              // (n*TI+ti)*TT + t
        int n = row / (TI * TT);
        int rem = row - n * (TI * TT);
        int ti = rem / TT;
        int t = rem - ti * TT;
        const float* pe = encb + (size_t)(ti * NB + n) * D + d8;
        const float* px = x + (size_t)(t * NB + n) * D + d8;
        f4 e0 = *(const f4*)pe, e1 = *(const f4*)(pe + 4);
        f4 x0 = *(const f4*)px, x1 = *(const f4*)(px + 4);
        u16* dst = Aj + (size_t)row * D + d8;
#pragma unroll
        for (int j = 0; j < 4; ++j) {
            dst[j] = f2bf(tanhf(e0[j] + x0[j]));
            dst[4 + j] = f2bf(tanhf(e1[j] + x1[j]));
        }
    } else {
        int idx = (bid - 8448) * 256 + threadIdx.x;      // 2048x512 / 8
        int d8 = (idx & 63) << 3;
        int row = idx >> 6;
        u16* dst = Bj + (size_t)row * D + d8;
        if (row < V) {
            const float* p = out_w + (size_t)row * D + d8;
            f4 a = *(const f4*)p, b = *(const f4*)(p + 4);
#pragma unroll
            for (int j = 0; j < 4; ++j) { dst[j] = f2bf(a[j]); dst[4 + j] = f2bf(b[j]); }
        } else {
#pragma unroll
            for (int j = 0; j < 8; ++j) dst[j] = 0;
        }
    }
}

// ---------------- joiner GEMM: out[MJ x 2000] = Aj * Bj^T (bf16 MFMA) -----
__global__ __launch_bounds__(256) void joiner_gemm(
    const u16* __restrict__ Aj, const u16* __restrict__ Bj,
    float* __restrict__ out)
{
    __shared__ u16 lsA[128 * 32];
    __shared__ u16 lsB[128 * 32];
    const int bid = blockIdx.x;
    const int mt = bid >> 4, nt = bid & 15;
    const int tid = threadIdx.x, lane = tid & 63, w = tid >> 6;
    const int wr = (w >> 1) * 64, wc = (w & 1) * 64;
    const int qd = lane >> 4, mm = lane & 15;
    f4 acc[4][4] = {};
    const u16* Abase = Aj + (size_t)mt * 128 * D;
    const u16* Bbase = Bj + (size_t)nt * 128 * D;

    for (int k0 = 0; k0 < D; k0 += 32) {
        __syncthreads();
#pragma unroll
        for (int i = 0; i < 2; ++i) {
            int idx = tid + i * 256;
            int row = idx >> 2, c = idx & 3;
            int chunk = c ^ ((row >> 1) & 3);
            async16(Abase + (size_t)row * D + k0 + chunk * 8, lsA + idx * 8);
            async16(Bbase + (size_t)row * D + k0 + chunk * 8, lsB + idx * 8);
        }
        __syncthreads();
        shortx8 af[4], bf[4];
#pragma unroll
        for (int rt = 0; rt < 4; ++rt) {
            int row = wr + rt * 16 + mm;
            int cpos = qd ^ ((row >> 1) & 3);
            af[rt] = *(const shortx8*)(lsA + row * 32 + cpos * 8);
        }
#pragma unroll
        for (int ct = 0; ct < 4; ++ct) {
            int col = wc + ct * 16 + mm;
            int cpos = qd ^ ((col >> 1) & 3);
            bf[ct] = *(const shortx8*)(lsB + col * 32 + cpos * 8);
        }
#pragma unroll
        for (int rt = 0; rt < 4; ++rt)
#pragma unroll
            for (int ct = 0; ct < 4; ++ct)
                acc[rt][ct] = mfma16(af[rt], bf[ct], acc[rt][ct]);
    }
#pragma unroll
    for (int rt = 0; rt < 4; ++rt)
#pragma unroll
        for (int ct = 0; ct < 4; ++ct)
#pragma unroll
            for (int reg = 0; reg < 4; ++reg) {
                int grow = mt * 128 + wr + rt * 16 + qd * 4 + reg;
                int gcol = nt * 128 + wc + ct * 16 + mm;
                if (gcol < V) out[(size_t)grow * V + gcol] = acc[rt][ct][reg];
            }
}

// --------------------------------------------------------------------------
extern "C" void kernel_launch(void* const* d_in, const int* in_sizes, int n_in,
                              void* d_out, int out_size, void* d_ws, size_t ws_size,
                              hipStream_t stream)
{
    const float* enc_out = (const float*)d_in[0];
    const float* embed_w = (const float*)d_in[1];
    const float* enc_w   = (const float*)d_in[2];
    const float* enc_b   = (const float*)d_in[3];
    const float* qkv_w   = (const float*)d_in[4];
    const float* qkv_b   = (const float*)d_in[5];
    const float* o_w     = (const float*)d_in[6];
    const float* o_b     = (const float*)d_in[7];
    const float* ln1_s   = (const float*)d_in[8];
    const float* ln1_b   = (const float*)d_in[9];
    const float* ff1_w   = (const float*)d_in[10];
    const float* ff1_b   = (const float*)d_in[11];
    const float* ff2_w   = (const float*)d_in[12];
    const float* ff2_b   = (const float*)d_in[13];
    const float* ln2_s   = (const float*)d_in[14];
    const float* ln2_b   = (const float*)d_in[15];
    const float* out_w   = (const float*)d_in[16];
    const int*   tgt_pad = (const int*)d_in[17];
    const int*   tgt_len = (const int*)d_in[18];
    const int*   sos     = (const int*)d_in[19];

    float* ws = (float*)d_ws;
    float* x    = ws;                  // 264x512 = 135168 f
    float* qkvb = ws + 135168;         // 264x1536 = 405504 f
    unsigned* bar = (unsigned*)(ws + 540672);   // old tmp slot (unused now)
    float* part = ws + 675840;         // 4x264x512 = 540672 f
    float* encb = ws + 1216512;        // 1024x512 = 524288 f
    u16* u  = (u16*)(ws + 1740800);
    u16* xh = u;                  u16* xl = xh + 320 * 512;     // padded to 320 rows
    u16* oh = xl + 163840;        u16* ol = oh + 163840;
    u16* hh = ol + 163840;        u16* hl = hh + 320 * 2048;    // 655360 each
    u16* eh = hl + 655360;        u16* el = eh + 524288;        // 1024x512
    u16* Wh = el + 524288;        u16* Wl = Wh + 19136512;
    u16* Aj = Wl + 19136512;      u16* Bj = Aj + (size_t)MJ * D;

    fused_convert<<<19728, 256, 0, stream>>>(
        qkv_w, o_w, ff1_w, ff2_w, enc_w, Wh, Wl,
        enc_out, eh, el, embed_w, tgt_pad, sos, x, xh, xl, bar);

    decoder_coop<<<GRID, 256, 0, stream>>>(
        Wh, Wl, qkv_b, o_b, ln1_s, ln1_b, ff1_b, ff2_b, ln2_s, ln2_b,
        enc_b, tgt_len, x, qkvb, part, encb,
        xh, xl, oh, ol, hh, hl, eh, el, bar);

    prep_joiner<<<8960, 256, 0, stream>>>(encb, x, Aj, out_w, Bj);

    joiner_gemm<<<264 * 16, 256, 0, stream>>>(Aj, Bj, (float*)d_out);
}

// Round 2
// 1160.717 us; speedup vs baseline: 1.4507x; 1.4507x over previous
//
#include <hip/hip_runtime.h>
#include <hip/hip_bf16.h>
#include <math.h>

// Problem dims
#define TI 128
#define NB 8
#define TO 32
#define TT 33      // TO+1
#define D 512
#define NH 8
#define HD 64
#define FF 2048
#define V 2000
#define NL 6
#define NTOK (TT*NB)   // 264 tokens, row = t*NB + n
#define MJ (NB*TI*TT)  // 33792 joiner rows, row = (n*TI+ti)*TT + t
#define GRID 256       // resident-grid size for the fused decoder

typedef __attribute__((ext_vector_type(4))) float  f4;
typedef __attribute__((ext_vector_type(8))) short  shortx8;
typedef unsigned short u16;

// weight plane element offsets inside Wh/Wl
static constexpr size_t QO = 0;              // + l*786432   (1536x512)
static constexpr size_t OO = 4718592;        // + l*262144   (512x512)
static constexpr size_t F1 = 6291456;        // + l*1048576  (2048x512)
static constexpr size_t F2 = 12582912;       // + l*1048576  (512x2048)
static constexpr size_t EW = 18874368;       // 512x512

__device__ __forceinline__ u16 f2bf(float f) {
    unsigned u = __float_as_uint(f);
    unsigned r = (u + 0x7fffu + ((u >> 16) & 1u)) >> 16;
    return (u16)r;
}
__device__ __forceinline__ float bf2f(u16 h) {
    return __uint_as_float(((unsigned)h) << 16);
}
__device__ __forceinline__ float wsum(float v) {
#pragma unroll
    for (int off = 32; off; off >>= 1) v += __shfl_xor(v, off, 64);
    return v;
}
__device__ __forceinline__ float wmax(float v) {
#pragma unroll
    for (int off = 32; off; off >>= 1) v = fmaxf(v, __shfl_xor(v, off, 64));
    return v;
}
__device__ __forceinline__ f4 mfma16(shortx8 a, shortx8 b, f4 c) {
    return __builtin_amdgcn_mfma_f32_16x16x32_bf16(a, b, c, 0, 0, 0);
}
__device__ __forceinline__ void async16(const void* g, void* l) {
    __builtin_amdgcn_global_load_lds(
        (const __attribute__((address_space(1))) unsigned int*)g,
        (__attribute__((address_space(3))) unsigned int*)l, 16, 0, 0);
}

// ---------------- hierarchical resident-grid barrier ----------------------
// Release: the LAST arriver per XCD (leader) writes back its XCD's L2 once
// (buffer_wbl2), then arrives on the global counter. Global count full =>
// all stores of all blocks are at MALL. Acquire: leader invalidates its
// XCD's L2+L1 (buffer_inv sc1), posts xdn; other blocks wait xdn, then
// invalidate their own L1 (buffer_inv sc0). Heavy L2 ops: 16/barrier
// instead of 512 (round-1's per-block __threadfence pair).
// Counters are monotonic; gs = 1-based sync index. Co-residency: 256 blocks,
// 48 KiB LDS, __launch_bounds__(256,1) -> 1 block/CU on 256 CUs.
__device__ __forceinline__ void grid_sync(unsigned gs, unsigned xcc, unsigned nblk,
                                          unsigned* gbar, unsigned* xarr,
                                          unsigned* xdn)
{
    __syncthreads();   // drains vmcnt/lgkmcnt for all waves of this block
    if (threadIdx.x == 0) {
        unsigned a = __hip_atomic_fetch_add(&xarr[xcc * 16], 1u, __ATOMIC_RELAXED,
                                            __HIP_MEMORY_SCOPE_AGENT);
        bool leader = (a == gs * nblk - 1);   // last arriver on this XCD
        if (leader)
            asm volatile("buffer_wbl2 sc1\n\ts_waitcnt vmcnt(0)" ::: "memory");
        __hip_atomic_fetch_add(gbar, 1u, __ATOMIC_RELAXED, __HIP_MEMORY_SCOPE_AGENT);
        unsigned tgt = (gs + 1) * (unsigned)GRID;   // init pass consumed GRID
        while (__hip_atomic_load(gbar, __ATOMIC_RELAXED,
                                 __HIP_MEMORY_SCOPE_AGENT) < tgt)
            __builtin_amdgcn_s_sleep(2);
        if (leader) {
            asm volatile("buffer_inv sc1\n\ts_waitcnt vmcnt(0)" ::: "memory");
            __hip_atomic_fetch_add(&xdn[xcc * 16], 1u, __ATOMIC_RELAXED,
                                   __HIP_MEMORY_SCOPE_AGENT);
        } else {
            while (__hip_atomic_load(&xdn[xcc * 16], __ATOMIC_RELAXED,
                                     __HIP_MEMORY_SCOPE_AGENT) < gs)
                __builtin_amdgcn_s_sleep(2);
            asm volatile("buffer_inv sc0\n\ts_waitcnt vmcnt(0)" ::: "memory");
        }
    }
    __syncthreads();
}

// ---------------- fused pre-pass: weight split + enc split + embed --------
__global__ __launch_bounds__(256) void fused_convert(
    const float* __restrict__ qw, const float* __restrict__ ow,
    const float* __restrict__ f1w, const float* __restrict__ f2w,
    const float* __restrict__ ew, u16* __restrict__ Wh, u16* __restrict__ Wl,
    const float* __restrict__ enc_out, u16* __restrict__ eh, u16* __restrict__ el,
    const float* __restrict__ emb, const int* __restrict__ tgt_pad,
    const int* __restrict__ sos, float* __restrict__ x,
    u16* __restrict__ xh, u16* __restrict__ xl, unsigned* __restrict__ bar)
{
    const int bid = blockIdx.x, tid = threadIdx.x;
    if (bid == 0) { bar[tid] = 0; bar[tid + 256] = 0; }   // zero barrier state
    if (bid < 18688) {
        int i4 = bid * 256 + tid;   // 4784128 total f4 units
        const float* src; int loc;
        if (i4 < 1179648)      { src = qw;  loc = i4; }
        else if (i4 < 1572864) { src = ow;  loc = i4 - 1179648; }
        else if (i4 < 3145728) { src = f1w; loc = i4 - 1572864; }
        else if (i4 < 4718592) { src = f2w; loc = i4 - 3145728; }
        else                   { src = ew;  loc = i4 - 4718592; }
        f4 v = *(const f4*)(src + (size_t)loc * 4);
        ushort4 h, l;
        h.x = f2bf(v[0]); l.x = f2bf(v[0] - bf2f(h.x));
        h.y = f2bf(v[1]); l.y = f2bf(v[1] - bf2f(h.y));
        h.z = f2bf(v[2]); l.z = f2bf(v[2] - bf2f(h.z));
        h.w = f2bf(v[3]); l.w = f2bf(v[3] - bf2f(h.w));
        *(ushort4*)(Wh + (size_t)i4 * 4) = h;
        *(ushort4*)(Wl + (size_t)i4 * 4) = l;
    } else if (bid < 19200) {
        int i = (bid - 18688) * 256 + tid;   // 131072 f4 units
        f4 v = *(const f4*)(enc_out + (size_t)i * 4);
        ushort4 h, l;
        h.x = f2bf(v[0]); l.x = f2bf(v[0] - bf2f(h.x));
        h.y = f2bf(v[1]); l.y = f2bf(v[1] - bf2f(h.y));
        h.z = f2bf(v[2]); l.z = f2bf(v[2] - bf2f(h.z));
        h.w = f2bf(v[3]); l.w = f2bf(v[3] - bf2f(h.w));
        *(ushort4*)(eh + (size_t)i * 4) = h;
        *(ushort4*)(el + (size_t)i * 4) = l;
    } else {
        int idx = (bid - 19200) * 256 + tid;   // NTOK*D = 135168
        if (idx < NTOK * D) {
            int d = idx & (D - 1);
            int row = idx >> 9;
            int t = row >> 3, n = row & 7;
            int tok = (t == 0) ? *sos : tgt_pad[n * TO + t - 1];
            float freq = __expf((float)(d & ~1) * (-0.017988946039015984f));
            float ang = (float)t * freq;
            float pe = (d & 1) ? cosf(ang) : sinf(ang);
            float v = emb[tok * D + d] * 22.627416997969522f + pe;
            x[idx] = v;
            u16 h = f2bf(v);
            xh[idx] = h;
            xl[idx] = f2bf(v - bf2f(h));
        }
    }
}

// ---------------- bf16 hi/lo GEMM tile body (device fn) -------------------
// 64x64 tile, BK=32, depth-2 pipelined staging (3 LDS buffers, counted
// vmcnt, raw s_barrier), chunk-XOR LDS swizzle (pre-swizzled global source
// + swizzled ds_read; global_load_lds dest stays linear). 3-product split
// MFMA (~fp32 accuracy).
// MODE 0: fp32 out + bias. MODE 1: fp32 split-K partial (slice zz, C offset
// zz*M*ldc, k-base zz*ksteps*32), no bias. MODE 2: bf16 hi/lo + bias + relu.
template<int MODE>
__device__ void gemm_tile(
    u16 (*ls)[4][2048], int mt, int nt, int zz,
    const u16* __restrict__ Ah, const u16* __restrict__ Al, int lda,
    const u16* __restrict__ Bh, const u16* __restrict__ Bl, int ldb,
    const float* __restrict__ bias,
    float* __restrict__ C, u16* __restrict__ Ch, u16* __restrict__ Cl,
    int M, int ldc, int ksteps)
{
    const int tid = threadIdx.x, lane = tid & 63, w = tid >> 6;
    const int wr = (w >> 1) * 32, wc = (w & 1) * 32;
    const int m0 = mt * 64, n0 = nt * 64;
    const int qd = lane >> 4, mm = lane & 15;
    const int kb = (MODE == 1) ? zz * ksteps * 32 : 0;
    f4 acc[2][2] = {};
    const u16* Ab  = Ah + (size_t)m0 * lda + kb;
    const u16* Alb = Al + (size_t)m0 * lda + kb;
    const u16* Bb  = Bh + (size_t)n0 * ldb + kb;
    const u16* Blb = Bl + (size_t)n0 * ldb + kb;
    const int srow = tid >> 2;                        // 0..63 tile row
    const int sc8  = ((tid & 3) ^ (srow & 3)) * 8;    // swizzled source chunk

    auto stage = [&](int b, int it) {
        int k0 = it * 32;
        async16(Ab  + (size_t)srow * lda + k0 + sc8, &ls[b][0][tid * 8]);
        async16(Alb + (size_t)srow * lda + k0 + sc8, &ls[b][1][tid * 8]);
        async16(Bb  + (size_t)srow * ldb + k0 + sc8, &ls[b][2][tid * 8]);
        async16(Blb + (size_t)srow * ldb + k0 + sc8, &ls[b][3][tid * 8]);
    };

    stage(0, 0);
    if (ksteps > 1) stage(1, 1);
    for (int it = 0; it < ksteps; ++it) {
        if (it + 1 < ksteps) asm volatile("s_waitcnt vmcnt(4)" ::: "memory");
        else                 asm volatile("s_waitcnt vmcnt(0)" ::: "memory");
        __builtin_amdgcn_s_barrier();
        if (it + 2 < ksteps) stage((it + 2) % 3, it + 2);
        const int cur = it % 3;
        shortx8 aH[2], aL[2], bH[2], bL[2];
#pragma unroll
        for (int rt = 0; rt < 2; ++rt) {
            int row = wr + rt * 16 + mm;
            int ca = (qd ^ (row & 3)) * 8;
            aH[rt] = *(const shortx8*)&ls[cur][0][row * 32 + ca];
            aL[rt] = *(const shortx8*)&ls[cur][1][row * 32 + ca];
            int col = wc + rt * 16 + mm;
            int cb = (qd ^ (col & 3)) * 8;
            bH[rt] = *(const shortx8*)&ls[cur][2][col * 32 + cb];
            bL[rt] = *(const shortx8*)&ls[cur][3][col * 32 + cb];
        }
#pragma unroll
        for (int rt = 0; rt < 2; ++rt)
#pragma unroll
            for (int ct = 0; ct < 2; ++ct) {
                acc[rt][ct] = mfma16(aH[rt], bH[ct], acc[rt][ct]);
                acc[rt][ct] = mfma16(aH[rt], bL[ct], acc[rt][ct]);
                acc[rt][ct] = mfma16(aL[rt], bH[ct], acc[rt][ct]);
            }
    }
    float* Cz = C;
    if (MODE == 1) Cz = C + (size_t)zz * (size_t)M * ldc;
#pragma unroll
    for (int rt = 0; rt < 2; ++rt)
#pragma unroll
        for (int ct = 0; ct < 2; ++ct)
#pragma unroll
            for (int reg = 0; reg < 4; ++reg) {
                int grow = m0 + wr + rt * 16 + qd * 4 + reg;
                int gcol = n0 + wc + ct * 16 + mm;
                if (grow < M) {
                    float v = acc[rt][ct][reg];
                    if (MODE != 1) v += bias[gcol];
                    if (MODE == 2) {
                        v = fmaxf(v, 0.f);
                        u16 h = f2bf(v);
                        Ch[(size_t)grow * ldc + gcol] = h;
                        Cl[(size_t)grow * ldc + gcol] = f2bf(v - bf2f(h));
                    } else {
                        Cz[(size_t)grow * ldc + gcol] = v;
                    }
                }
            }
}

// ---------------- attention body (one "block slot" per (n,h)) -------------
__device__ void attn_body(u16* lsr, int bid,
                          const float* __restrict__ qkv,
                          const int* __restrict__ tgt_len,
                          u16* __restrict__ oh, u16* __restrict__ ol)
{
    const int n = bid >> 3, h = bid & 7;
    const int tid = threadIdx.x, lane = tid & 63, w = tid >> 6;
    float* sq  = (float*)lsr;          // [t][d]   TT*HD
    float* skT = sq + TT * HD;         // [d][t]   HD*TT
    float* sv  = skT + HD * TT;        // [t][d]   TT*HD
    for (int idx = tid; idx < TT * HD; idx += 256) {
        int t = idx >> 6, d = idx & 63;
        size_t base = (size_t)(t * NB + n) * (3 * D) + h * HD + d;
        sq[idx] = qkv[base] * 0.125f;          // 1/sqrt(64)
        skT[d * TT + t] = qkv[base + D];
        sv[idx] = qkv[base + 2 * D];
    }
    int len = max(tgt_len[n], 1);
    __syncthreads();
    for (int r = w; r < TT; r += 4) {
        bool ok = (lane < TT) && (lane <= r) && (lane < len);
        float s = -INFINITY;
        if (ok) {
            float dot = 0.f;
#pragma unroll 8
            for (int d = 0; d < HD; ++d) dot += sq[r * HD + d] * skT[d * TT + lane];
            s = dot;
        }
        float mx = wmax(s);
        float e = ok ? __expf(s - mx) : 0.f;
        float sum = wsum(e);
        float att = e / sum;
        float o = 0.f;
#pragma unroll
        for (int k = 0; k < TT; ++k) {
            float a = __shfl(att, k, 64);
            o += a * sv[k * HD + lane];
        }
        size_t oi = (size_t)(r * NB + n) * D + h * HD + lane;
        u16 hv = f2bf(o);
        oh[oi] = hv;
        ol[oi] = f2bf(o - bf2f(hv));
    }
}

// ---------------- residual add (+NP partials) + LayerNorm body ------------
template<int NP, int BIAS>
__device__ void add_ln_body(int bid,
    float* __restrict__ x, const float* __restrict__ r,
    const float* __restrict__ bias2,
    const float* __restrict__ s, const float* __restrict__ b,
    u16* __restrict__ xh, u16* __restrict__ xl)
{
    int row = bid * 4 + (threadIdx.x >> 6);
    int lane = threadIdx.x & 63;
    if (row >= NTOK) return;
    float* xr = x + (size_t)row * D;
    f4 v1 = *(const f4*)(xr + lane * 4);
    f4 v2 = *(const f4*)(xr + 256 + lane * 4);
#pragma unroll
    for (int p = 0; p < NP; ++p) {
        const float* rr = r + (size_t)p * (NTOK * D) + (size_t)row * D;
        v1 += *(const f4*)(rr + lane * 4);
        v2 += *(const f4*)(rr + 256 + lane * 4);
    }
    if (BIAS) {
        v1 += *(const f4*)(bias2 + lane * 4);
        v2 += *(const f4*)(bias2 + 256 + lane * 4);
    }
    float sum = 0.f, sq = 0.f;
#pragma unroll
    for (int j = 0; j < 4; ++j) {
        sum += v1[j] + v2[j];
        sq += v1[j] * v1[j] + v2[j] * v2[j];
    }
    sum = wsum(sum); sq = wsum(sq);
    float mean = sum * (1.f / D);
    float var = sq * (1.f / D) - mean * mean;
    float rstd = rsqrtf(var + 1e-5f);
    f4 o1, o2;
    ushort4 h1, l1, h2, l2;
    u16 th, tl;
#pragma unroll
    for (int j = 0; j < 4; ++j) {
        int c1 = lane * 4 + j, c2 = c1 + 256;
        o1[j] = (v1[j] - mean) * rstd * s[c1] + b[c1];
        o2[j] = (v2[j] - mean) * rstd * s[c2] + b[c2];
    }
    th = f2bf(o1[0]); tl = f2bf(o1[0] - bf2f(th)); h1.x = th; l1.x = tl;
    th = f2bf(o1[1]); tl = f2bf(o1[1] - bf2f(th)); h1.y = th; l1.y = tl;
    th = f2bf(o1[2]); tl = f2bf(o1[2] - bf2f(th)); h1.z = th; l1.z = tl;
    th = f2bf(o1[3]); tl = f2bf(o1[3] - bf2f(th)); h1.w = th; l1.w = tl;
    th = f2bf(o2[0]); tl = f2bf(o2[0] - bf2f(th)); h2.x = th; l2.x = tl;
    th = f2bf(o2[1]); tl = f2bf(o2[1] - bf2f(th)); h2.y = th; l2.y = tl;
    th = f2bf(o2[2]); tl = f2bf(o2[2] - bf2f(th)); h2.z = th; l2.z = tl;
    th = f2bf(o2[3]); tl = f2bf(o2[3] - bf2f(th)); h2.w = th; l2.w = tl;
    *(f4*)(xr + lane * 4) = o1;
    *(f4*)(xr + 256 + lane * 4) = o2;
    *(ushort4*)(xh + (size_t)row * D + lane * 4) = h1;
    *(ushort4*)(xl + (size_t)row * D + lane * 4) = l1;
    *(ushort4*)(xh + (size_t)row * D + 256 + lane * 4) = h2;
    *(ushort4*)(xl + (size_t)row * D + 256 + lane * 4) = l2;
}

// ---------------- fused 6-layer decoder (resident grid, atomic barriers) --
// Stage tile->block maps are XCD-chunked: blocks sharing a weight panel get
// the same (bid & 7) so panel re-reads hit the XCD-local L2 (any bijection
// is correct; the %8 placement assumption only affects locality).
__global__ __launch_bounds__(256, 1) void decoder_coop(
    const u16* __restrict__ Wh, const u16* __restrict__ Wl,
    const float* __restrict__ qkv_b, const float* __restrict__ o_b,
    const float* __restrict__ ln1_s, const float* __restrict__ ln1_b,
    const float* __restrict__ ff1_b, const float* __restrict__ ff2_b,
    const float* __restrict__ ln2_s, const float* __restrict__ ln2_b,
    const float* __restrict__ enc_b, const int* __restrict__ tgt_len,
    float* __restrict__ x, float* __restrict__ qkvb,
    float* __restrict__ part, float* __restrict__ encb,
    u16* __restrict__ xh, u16* __restrict__ xl,
    u16* __restrict__ oh, u16* __restrict__ ol,
    u16* __restrict__ hh, u16* __restrict__ hl,
    const u16* __restrict__ eh, const u16* __restrict__ el,
    unsigned* __restrict__ bar)
{
    __shared__ u16 ls[3][4][2048];   // 48 KiB: 3-deep staging; fp32 for attn
    const int bid = blockIdx.x;
    const int tid = threadIdx.x;

    unsigned xcc;
    asm("s_getreg_b32 %0, hwreg(HW_REG_XCC_ID, 0, 4)" : "=s"(xcc));
    xcc &= 7;
    unsigned* gbar = bar;            // [0]
    unsigned* xcnt = bar + 16;       // 8 x stride-16
    unsigned* xarr = bar + 144;
    unsigned* xdn  = bar + 272;

    // init: count blocks per XCD, then one plain global barrier
    __shared__ unsigned s_nblk;
    if (tid == 0) {
        __hip_atomic_fetch_add(&xcnt[xcc * 16], 1u, __ATOMIC_RELAXED,
                               __HIP_MEMORY_SCOPE_AGENT);
        __hip_atomic_fetch_add(gbar, 1u, __ATOMIC_RELAXED, __HIP_MEMORY_SCOPE_AGENT);
        while (__hip_atomic_load(gbar, __ATOMIC_RELAXED,
                                 __HIP_MEMORY_SCOPE_AGENT) < (unsigned)GRID)
            __builtin_amdgcn_s_sleep(2);
        s_nblk = __hip_atomic_load(&xcnt[xcc * 16], __ATOMIC_RELAXED,
                                   __HIP_MEMORY_SCOPE_AGENT);
    }
    __syncthreads();
    const unsigned nblk = s_nblk;
    unsigned gs = 0;

    const int xg = bid & 7, jg = bid >> 3;

    for (int l = 0; l < NL; ++l) {
        const u16* WqH = Wh + QO + (size_t)l * 786432;
        const u16* WqL = Wl + QO + (size_t)l * 786432;
        const u16* WoH = Wh + OO + (size_t)l * 262144;
        const u16* WoL = Wl + OO + (size_t)l * 262144;
        const u16* W1H = Wh + F1 + (size_t)l * 1048576;
        const u16* W1L = Wl + F1 + (size_t)l * 1048576;
        const u16* W2H = Wh + F2 + (size_t)l * 1048576;
        const u16* W2L = Wl + F2 + (size_t)l * 1048576;

        // S1: qkv projection (120 blocks); layer 0 also runs the enc GEMM
        if (bid < 120) {
            int mt = jg % 5, nt = (jg / 5) * 8 + xg;   // same-nt -> same XCD
            gemm_tile<0>(ls, mt, nt, 0,
                         xh, xl, 512, WqH, WqL, 512,
                         qkv_b + l * 1536, qkvb, nullptr, nullptr,
                         NTOK, 1536, 16);
        } else if (l == 0 && bid < 248) {
            int t = bid - 120;   // 16 row-tiles x 8 col-tiles (nt = t&7 = XCD)
            gemm_tile<0>(ls, t >> 3, t & 7, 0,
                         eh, el, 512, Wh + EW, Wl + EW, 512,
                         enc_b, encb, nullptr, nullptr,
                         TI * NB, 512, 16);
        }
        grid_sync(++gs, xcc, nblk, gbar, xarr, xdn);

        // S2: attention
        if (bid < NB * NH) attn_body((u16*)ls, bid, qkvb, tgt_len, oh, ol);
        grid_sync(++gs, xcc, nblk, gbar, xarr, xdn);

        // S3: o-projection, split-K x4 (K=512 -> 4 slices of 128)
        if (bid < 160) {
            int z = jg % 4, mt = jg / 4, nt = xg;
            gemm_tile<1>(ls, mt, nt, z,
                         oh, ol, 512, WoH, WoL, 512,
                         nullptr, part, nullptr, nullptr,
                         NTOK, 512, 4);
        }
        grid_sync(++gs, xcc, nblk, gbar, xarr, xdn);

        // S4: x = LN(x + sum(part) + o_b)
        if (bid < 66) add_ln_body<4, 1>(bid, x, part, o_b + l * 512,
                                        ln1_s + l * 512, ln1_b + l * 512, xh, xl);
        grid_sync(++gs, xcc, nblk, gbar, xarr, xdn);

        // S5: ff1 + relu -> bf16 hi/lo
        if (bid < 160) {
            int mt = jg % 5, nt = (jg / 5) * 8 + xg;
            gemm_tile<2>(ls, mt, nt, 0,
                         xh, xl, 512, W1H, W1L, 512,
                         ff1_b + l * 2048, nullptr, hh, hl,
                         NTOK, 2048, 16);
        }
        grid_sync(++gs, xcc, nblk, gbar, xarr, xdn);

        // S6: ff2, split-K x4 (K=2048 -> 4 slices of 512)
        if (bid < 160) {
            int z = jg % 4, mt = jg / 4, nt = xg;
            gemm_tile<1>(ls, mt, nt, z,
                         hh, hl, 2048, W2H, W2L, 2048,
                         nullptr, part, nullptr, nullptr,
                         NTOK, 512, 16);
        }
        grid_sync(++gs, xcc, nblk, gbar, xarr, xdn);

        // S7: x = LN(x + sum(part) + ff2_b)
        if (bid < 66) add_ln_body<4, 1>(bid, x, part, ff2_b + l * 512,
                                        ln2_s + l * 512, ln2_b + l * 512, xh, xl);
        if (l < NL - 1) grid_sync(++gs, xcc, nblk, gbar, xarr, xdn);
    }
}

// ---------------- joiner prep: A = bf16(tanh(enc + x)), B = bf16(out_w) ---
__global__ __launch_bounds__(256) void prep_joiner(
    const float* __restrict__ encb, const float* __restrict__ x,
    u16* __restrict__ Aj, const float* __restrict__ out_w, u16* __restrict__ Bj)
{
    const int bid = blockIdx.x;
    if (bid < 8448) {
        int idx = bid * 256 + threadIdx.x;
        int d8 = (idx & 63) << 3;
        int row = idx >> 6;                              // (n*TI+ti)*TT + t
        int n = row / (TI * TT);
        int rem = row - n * (TI * TT);
        int ti = rem / TT;
        int t = rem - ti * TT;
        const float* pe = encb + (size_t)(ti * NB + n) * D + d8;
        const float* px = x + (size_t)(t * NB + n) * D + d8;
        f4 e0 = *(const f4*)pe, e1 = *(const f4*)(pe + 4);
        f4 x0 = *(const f4*)px, x1 = *(const f4*)(px + 4);
        u16* dst = Aj + (size_t)row * D + d8;
#pragma unroll
        for (int j = 0; j < 4; ++j) {
            dst[j] = f2bf(tanhf(e0[j] + x0[j]));
            dst[4 + j] = f2bf(tanhf(e1[j] + x1[j]));
        }
    } else {
        int idx = (bid - 8448) * 256 + threadIdx.x;      // 2048x512 / 8
        int d8 = (idx & 63) << 3;
        int row = idx >> 6;
        u16* dst = Bj + (size_t)row * D + d8;
        if (row < V) {
            const float* p = out_w + (size_t)row * D + d8;
            f4 a = *(const f4*)p, b = *(const f4*)(p + 4);
#pragma unroll
            for (int j = 0; j < 4; ++j) { dst[j] = f2bf(a[j]); dst[4 + j] = f2bf(b[j]); }
        } else {
#pragma unroll
            for (int j = 0; j < 8; ++j) dst[j] = 0;
        }
    }
}

// ---------------- joiner GEMM: out[MJ x 2000] = Aj * Bj^T (bf16 MFMA) -----
// XCD-chunked remap: each XCD owns 33 A-panels (all 16 n-tiles of each),
// so the A panel is fetched from MALL once per XCD instead of 16x.
// Depth-2 pipelined staging, nontemporal output stores.
__global__ __launch_bounds__(256) void joiner_gemm(
    const u16* __restrict__ Aj, const u16* __restrict__ Bj,
    float* __restrict__ out)
{
    __shared__ u16 lsA[3][128 * 32];
    __shared__ u16 lsB[3][128 * 32];
    const int bid = blockIdx.x;
    const int v = (bid & 7) * 528 + (bid >> 3);   // 4224 = 8 * 528, bijective
    const int mt = v >> 4, nt = v & 15;
    const int tid = threadIdx.x, lane = tid & 63, w = tid >> 6;
    const int wr = (w >> 1) * 64, wc = (w & 1) * 64;
    const int qd = lane >> 4, mm = lane & 15;
    f4 acc[4][4] = {};
    const u16* Abase = Aj + (size_t)mt * 128 * D;
    const u16* Bbase = Bj + (size_t)nt * 128 * D;

    auto stage = [&](int b, int it) {
        int k0 = it * 32;
#pragma unroll
        for (int i = 0; i < 2; ++i) {
            int idx = tid + i * 256;
            int row = idx >> 2, c = idx & 3;
            int chunk = c ^ ((row >> 1) & 3);
            async16(Abase + (size_t)row * D + k0 + chunk * 8, &lsA[b][idx * 8]);
            async16(Bbase + (size_t)row * D + k0 + chunk * 8, &lsB[b][idx * 8]);
        }
    };
    stage(0, 0);
    stage(1, 1);
    for (int it = 0; it < 16; ++it) {
        if (it < 15) asm volatile("s_waitcnt vmcnt(4)" ::: "memory");
        else         asm volatile("s_waitcnt vmcnt(0)" ::: "memory");
        __builtin_amdgcn_s_barrier();
        if (it + 2 < 16) stage((it + 2) % 3, it + 2);
        const int cur = it % 3;
        shortx8 af[4], bf[4];
#pragma unroll
        for (int rt = 0; rt < 4; ++rt) {
            int row = wr + rt * 16 + mm;
            int cpos = qd ^ ((row >> 1) & 3);
            af[rt] = *(const shortx8*)&lsA[cur][row * 32 + cpos * 8];
        }
#pragma unroll
        for (int ct = 0; ct < 4; ++ct) {
            int col = wc + ct * 16 + mm;
            int cpos = qd ^ ((col >> 1) & 3);
            bf[ct] = *(const shortx8*)&lsB[cur][col * 32 + cpos * 8];
        }
#pragma unroll
        for (int rt = 0; rt < 4; ++rt)
#pragma unroll
            for (int ct = 0; ct < 4; ++ct)
                acc[rt][ct] = mfma16(af[rt], bf[ct], acc[rt][ct]);
    }
#pragma unroll
    for (int rt = 0; rt < 4; ++rt)
#pragma unroll
        for (int ct = 0; ct < 4; ++ct)
#pragma unroll
            for (int reg = 0; reg < 4; ++reg) {
                int grow = mt * 128 + wr + rt * 16 + qd * 4 + reg;
                int gcol = nt * 128 + wc + ct * 16 + mm;
                if (gcol < V)
                    __builtin_nontemporal_store(acc[rt][ct][reg],
                                                &out[(size_t)grow * V + gcol]);
            }
}

// --------------------------------------------------------------------------
extern "C" void kernel_launch(void* const* d_in, const int* in_sizes, int n_in,
                              void* d_out, int out_size, void* d_ws, size_t ws_size,
                              hipStream_t stream)
{
    const float* enc_out = (const float*)d_in[0];
    const float* embed_w = (const float*)d_in[1];
    const float* enc_w   = (const float*)d_in[2];
    const float* enc_b   = (const float*)d_in[3];
    const float* qkv_w   = (const float*)d_in[4];
    const float* qkv_b   = (const float*)d_in[5];
    const float* o_w     = (const float*)d_in[6];
    const float* o_b     = (const float*)d_in[7];
    const float* ln1_s   = (const float*)d_in[8];
    const float* ln1_b   = (const float*)d_in[9];
    const float* ff1_w   = (const float*)d_in[10];
    const float* ff1_b   = (const float*)d_in[11];
    const float* ff2_w   = (const float*)d_in[12];
    const float* ff2_b   = (const float*)d_in[13];
    const float* ln2_s   = (const float*)d_in[14];
    const float* ln2_b   = (const float*)d_in[15];
    const float* out_w   = (const float*)d_in[16];
    const int*   tgt_pad = (const int*)d_in[17];
    const int*   tgt_len = (const int*)d_in[18];
    const int*   sos     = (const int*)d_in[19];

    float* ws = (float*)d_ws;
    float* x    = ws;                  // 264x512 = 135168 f
    float* qkvb = ws + 135168;         // 264x1536 = 405504 f
    unsigned* bar = (unsigned*)(ws + 540672);   // 512 u32 barrier state
    float* part = ws + 675840;         // 4x264x512 = 540672 f
    float* encb = ws + 1216512;        // 1024x512 = 524288 f
    u16* u  = (u16*)(ws + 1740800);
    u16* xh = u;                  u16* xl = xh + 320 * 512;     // padded to 320 rows
    u16* oh = xl + 163840;        u16* ol = oh + 163840;
    u16* hh = ol + 163840;        u16* hl = hh + 320 * 2048;    // 655360 each
    u16* eh = hl + 655360;        u16* el = eh + 524288;        // 1024x512
    u16* Wh = el + 524288;        u16* Wl = Wh + 19136512;
    u16* Aj = Wl + 19136512;      u16* Bj = Aj + (size_t)MJ * D;

    fused_convert<<<19728, 256, 0, stream>>>(
        qkv_w, o_w, ff1_w, ff2_w, enc_w, Wh, Wl,
        enc_out, eh, el, embed_w, tgt_pad, sos, x, xh, xl, bar);

    decoder_coop<<<GRID, 256, 0, stream>>>(
        Wh, Wl, qkv_b, o_b, ln1_s, ln1_b, ff1_b, ff2_b, ln2_s, ln2_b,
        enc_b, tgt_len, x, qkvb, part, encb,
        xh, xl, oh, ol, hh, hl, eh, el, bar);

    prep_joiner<<<8960, 256, 0, stream>>>(encb, x, Aj, out_w, Bj);

    joiner_gemm<<<264 * 16, 256, 0, stream>>>(Aj, Bj, (float*)d_out);
}

// Round 3
// 964.413 us; speedup vs baseline: 1.7460x; 1.2035x over previous
//
#include <hip/hip_runtime.h>
#include <hip/hip_bf16.h>
#include <math.h>

// Problem dims
#define TI 128
#define NB 8
#define TO 32
#define TT 33      // TO+1
#define D 512
#define NH 8
#define HD 64
#define FF 2048
#define V 2000
#define NL 6
#define NTOK (TT*NB)   // 264 tokens, row = t*NB + n
#define MJ (NB*TI*TT)  // 33792 joiner rows, row = (n*TI+ti)*TT + t
#define GRID 256       // resident-grid size for the fused decoder

typedef __attribute__((ext_vector_type(4))) float  f4;
typedef __attribute__((ext_vector_type(8))) short  shortx8;
typedef unsigned short u16;

// weight plane element offsets inside Wh/Wl
static constexpr size_t QO = 0;              // + l*786432   (1536x512)
static constexpr size_t OO = 4718592;        // + l*262144   (512x512)
static constexpr size_t F1 = 6291456;        // + l*1048576  (2048x512)
static constexpr size_t F2 = 12582912;       // + l*1048576  (512x2048)
static constexpr size_t EW = 18874368;       // 512x512

__device__ __forceinline__ u16 f2bf(float f) {
    unsigned u = __float_as_uint(f);
    unsigned r = (u + 0x7fffu + ((u >> 16) & 1u)) >> 16;
    return (u16)r;
}
__device__ __forceinline__ float bf2f(u16 h) {
    return __uint_as_float(((unsigned)h) << 16);
}
__device__ __forceinline__ float wsum(float v) {
#pragma unroll
    for (int off = 32; off; off >>= 1) v += __shfl_xor(v, off, 64);
    return v;
}
__device__ __forceinline__ float wmax(float v) {
#pragma unroll
    for (int off = 32; off; off >>= 1) v = fmaxf(v, __shfl_xor(v, off, 64));
    return v;
}
__device__ __forceinline__ f4 mfma16(shortx8 a, shortx8 b, f4 c) {
    return __builtin_amdgcn_mfma_f32_16x16x32_bf16(a, b, c, 0, 0, 0);
}
__device__ __forceinline__ void async16(const void* g, void* l) {
    __builtin_amdgcn_global_load_lds(
        (const __attribute__((address_space(1))) unsigned int*)g,
        (__attribute__((address_space(3))) unsigned int*)l, 16, 0, 0);
}

// ---------------- tournament resident-grid barrier ------------------------
// Arrival: per-XCD counter (8 distinct 128B lines) -> <=32 serialized RMWs
// per line, in parallel across XCDs. The last arriver per XCD (leader) does
// ONE buffer_wbl2 (release: flush this XCD's dirty L2 to MALL), then ONE
// global-counter RMW (8 total, 8 pollers). When the global counter shows all
// XCDs arrived, each leader invalidates its XCD's L2 (acquire) and posts the
// per-XCD done counter; non-leaders poll their XCD's done line (<=31 pollers,
// 128-B separated) and invalidate their L1. Semantics identical to the
// twice-passed round-2 protocol; only the counter topology changed
// (256->8 participants on the hot global line).
// Counters monotonic; gs = 1-based sync index.
__device__ __forceinline__ void grid_sync(unsigned gs, unsigned xcc, unsigned nblk,
                                          unsigned nx, unsigned* gbar2,
                                          unsigned* xarr, unsigned* xdn)
{
    __syncthreads();   // drains vmcnt/lgkmcnt for all waves of this block
    if (threadIdx.x == 0) {
        unsigned a = __hip_atomic_fetch_add(&xarr[xcc * 32], 1u, __ATOMIC_RELAXED,
                                            __HIP_MEMORY_SCOPE_AGENT);
        if (a == gs * nblk - 1u) {   // last arriver on this XCD = leader
            asm volatile("buffer_wbl2 sc1\n\ts_waitcnt vmcnt(0)" ::: "memory");
            __hip_atomic_fetch_add(gbar2, 1u, __ATOMIC_RELAXED,
                                   __HIP_MEMORY_SCOPE_AGENT);
            while (__hip_atomic_load(gbar2, __ATOMIC_RELAXED,
                                     __HIP_MEMORY_SCOPE_AGENT) < gs * nx)
                __builtin_amdgcn_s_sleep(1);
            asm volatile("buffer_inv sc1\n\ts_waitcnt vmcnt(0)" ::: "memory");
            __hip_atomic_fetch_add(&xdn[xcc * 32], 1u, __ATOMIC_RELAXED,
                                   __HIP_MEMORY_SCOPE_AGENT);
        } else {
            while (__hip_atomic_load(&xdn[xcc * 32], __ATOMIC_RELAXED,
                                     __HIP_MEMORY_SCOPE_AGENT) < gs)
                __builtin_amdgcn_s_sleep(4);
            asm volatile("buffer_inv sc0\n\ts_waitcnt vmcnt(0)" ::: "memory");
        }
    }
    __syncthreads();
}

// ---------------- fused pre-pass: weight split + enc split + embed --------
__global__ __launch_bounds__(256) void fused_convert(
    const float* __restrict__ qw, const float* __restrict__ ow,
    const float* __restrict__ f1w, const float* __restrict__ f2w,
    const float* __restrict__ ew, u16* __restrict__ Wh, u16* __restrict__ Wl,
    const float* __restrict__ enc_out, u16* __restrict__ eh, u16* __restrict__ el,
    const float* __restrict__ emb, const int* __restrict__ tgt_pad,
    const int* __restrict__ sos, float* __restrict__ x,
    u16* __restrict__ xh, u16* __restrict__ xl, unsigned* __restrict__ bar)
{
    const int bid = blockIdx.x, tid = threadIdx.x;
    if (bid == 0) {   // zero 1024 u32 of barrier state
        bar[tid] = 0; bar[tid + 256] = 0; bar[tid + 512] = 0; bar[tid + 768] = 0;
    }
    if (bid < 18688) {
        int i4 = bid * 256 + tid;   // 4784128 total f4 units
        const float* src; int loc;
        if (i4 < 1179648)      { src = qw;  loc = i4; }
        else if (i4 < 1572864) { src = ow;  loc = i4 - 1179648; }
        else if (i4 < 3145728) { src = f1w; loc = i4 - 1572864; }
        else if (i4 < 4718592) { src = f2w; loc = i4 - 3145728; }
        else                   { src = ew;  loc = i4 - 4718592; }
        f4 v = *(const f4*)(src + (size_t)loc * 4);
        ushort4 h, l;
        h.x = f2bf(v[0]); l.x = f2bf(v[0] - bf2f(h.x));
        h.y = f2bf(v[1]); l.y = f2bf(v[1] - bf2f(h.y));
        h.z = f2bf(v[2]); l.z = f2bf(v[2] - bf2f(h.z));
        h.w = f2bf(v[3]); l.w = f2bf(v[3] - bf2f(h.w));
        *(ushort4*)(Wh + (size_t)i4 * 4) = h;
        *(ushort4*)(Wl + (size_t)i4 * 4) = l;
    } else if (bid < 19200) {
        int i = (bid - 18688) * 256 + tid;   // 131072 f4 units
        f4 v = *(const f4*)(enc_out + (size_t)i * 4);
        ushort4 h, l;
        h.x = f2bf(v[0]); l.x = f2bf(v[0] - bf2f(h.x));
        h.y = f2bf(v[1]); l.y = f2bf(v[1] - bf2f(h.y));
        h.z = f2bf(v[2]); l.z = f2bf(v[2] - bf2f(h.z));
        h.w = f2bf(v[3]); l.w = f2bf(v[3] - bf2f(h.w));
        *(ushort4*)(eh + (size_t)i * 4) = h;
        *(ushort4*)(el + (size_t)i * 4) = l;
    } else {
        int idx = (bid - 19200) * 256 + tid;   // NTOK*D = 135168
        if (idx < NTOK * D) {
            int d = idx & (D - 1);
            int row = idx >> 9;
            int t = row >> 3, n = row & 7;
            int tok = (t == 0) ? *sos : tgt_pad[n * TO + t - 1];
            float freq = __expf((float)(d & ~1) * (-0.017988946039015984f));
            float ang = (float)t * freq;
            float pe = (d & 1) ? cosf(ang) : sinf(ang);
            float v = emb[tok * D + d] * 22.627416997969522f + pe;
            x[idx] = v;
            u16 h = f2bf(v);
            xh[idx] = h;
            xl[idx] = f2bf(v - bf2f(h));
        }
    }
}

// ---------------- bf16 hi/lo GEMM tile body (device fn) -------------------
// 64x64 tile, BK=32, depth-2 pipelined staging (3 LDS buffers, counted
// vmcnt, raw s_barrier), chunk-XOR LDS swizzle (pre-swizzled global source
// + swizzled ds_read; global_load_lds dest stays linear). 3-product split
// MFMA (~fp32 accuracy).
// MODE 0: fp32 out + bias. MODE 1: fp32 split-K partial (slice zz, C offset
// zz*M*ldc, k-base zz*ksteps*32), no bias. MODE 2: bf16 hi/lo + bias + relu.
template<int MODE>
__device__ void gemm_tile(
    u16 (*ls)[4][2048], int mt, int nt, int zz,
    const u16* __restrict__ Ah, const u16* __restrict__ Al, int lda,
    const u16* __restrict__ Bh, const u16* __restrict__ Bl, int ldb,
    const float* __restrict__ bias,
    float* __restrict__ C, u16* __restrict__ Ch, u16* __restrict__ Cl,
    int M, int ldc, int ksteps)
{
    const int tid = threadIdx.x, lane = tid & 63, w = tid >> 6;
    const int wr = (w >> 1) * 32, wc = (w & 1) * 32;
    const int m0 = mt * 64, n0 = nt * 64;
    const int qd = lane >> 4, mm = lane & 15;
    const int kb = (MODE == 1) ? zz * ksteps * 32 : 0;
    f4 acc[2][2] = {};
    const u16* Ab  = Ah + (size_t)m0 * lda + kb;
    const u16* Alb = Al + (size_t)m0 * lda + kb;
    const u16* Bb  = Bh + (size_t)n0 * ldb + kb;
    const u16* Blb = Bl + (size_t)n0 * ldb + kb;
    const int srow = tid >> 2;                        // 0..63 tile row
    const int sc8  = ((tid & 3) ^ (srow & 3)) * 8;    // swizzled source chunk

    auto stage = [&](int b, int it) {
        int k0 = it * 32;
        async16(Ab  + (size_t)srow * lda + k0 + sc8, &ls[b][0][tid * 8]);
        async16(Alb + (size_t)srow * lda + k0 + sc8, &ls[b][1][tid * 8]);
        async16(Bb  + (size_t)srow * ldb + k0 + sc8, &ls[b][2][tid * 8]);
        async16(Blb + (size_t)srow * ldb + k0 + sc8, &ls[b][3][tid * 8]);
    };

    stage(0, 0);
    if (ksteps > 1) stage(1, 1);
    for (int it = 0; it < ksteps; ++it) {
        if (it + 1 < ksteps) asm volatile("s_waitcnt vmcnt(4)" ::: "memory");
        else                 asm volatile("s_waitcnt vmcnt(0)" ::: "memory");
        __builtin_amdgcn_s_barrier();
        if (it + 2 < ksteps) stage((it + 2) % 3, it + 2);
        const int cur = it % 3;
        shortx8 aH[2], aL[2], bH[2], bL[2];
#pragma unroll
        for (int rt = 0; rt < 2; ++rt) {
            int row = wr + rt * 16 + mm;
            int ca = (qd ^ (row & 3)) * 8;
            aH[rt] = *(const shortx8*)&ls[cur][0][row * 32 + ca];
            aL[rt] = *(const shortx8*)&ls[cur][1][row * 32 + ca];
            int col = wc + rt * 16 + mm;
            int cb = (qd ^ (col & 3)) * 8;
            bH[rt] = *(const shortx8*)&ls[cur][2][col * 32 + cb];
            bL[rt] = *(const shortx8*)&ls[cur][3][col * 32 + cb];
        }
#pragma unroll
        for (int rt = 0; rt < 2; ++rt)
#pragma unroll
            for (int ct = 0; ct < 2; ++ct) {
                acc[rt][ct] = mfma16(aH[rt], bH[ct], acc[rt][ct]);
                acc[rt][ct] = mfma16(aH[rt], bL[ct], acc[rt][ct]);
                acc[rt][ct] = mfma16(aL[rt], bH[ct], acc[rt][ct]);
            }
    }
    float* Cz = C;
    if (MODE == 1) Cz = C + (size_t)zz * (size_t)M * ldc;
#pragma unroll
    for (int rt = 0; rt < 2; ++rt)
#pragma unroll
        for (int ct = 0; ct < 2; ++ct)
#pragma unroll
            for (int reg = 0; reg < 4; ++reg) {
                int grow = m0 + wr + rt * 16 + qd * 4 + reg;
                int gcol = n0 + wc + ct * 16 + mm;
                if (grow < M) {
                    float v = acc[rt][ct][reg];
                    if (MODE != 1) v += bias[gcol];
                    if (MODE == 2) {
                        v = fmaxf(v, 0.f);
                        u16 h = f2bf(v);
                        Ch[(size_t)grow * ldc + gcol] = h;
                        Cl[(size_t)grow * ldc + gcol] = f2bf(v - bf2f(h));
                    } else {
                        Cz[(size_t)grow * ldc + gcol] = v;
                    }
                }
            }
}

// ---------------- attention body (one "block slot" per (n,h)) -------------
__device__ void attn_body(u16* lsr, int bid,
                          const float* __restrict__ qkv,
                          const int* __restrict__ tgt_len,
                          u16* __restrict__ oh, u16* __restrict__ ol)
{
    const int n = bid >> 3, h = bid & 7;
    const int tid = threadIdx.x, lane = tid & 63, w = tid >> 6;
    float* sq  = (float*)lsr;          // [t][d]   TT*HD
    float* skT = sq + TT * HD;         // [d][t]   HD*TT
    float* sv  = skT + HD * TT;        // [t][d]   TT*HD
    for (int idx = tid; idx < TT * HD; idx += 256) {
        int t = idx >> 6, d = idx & 63;
        size_t base = (size_t)(t * NB + n) * (3 * D) + h * HD + d;
        sq[idx] = qkv[base] * 0.125f;          // 1/sqrt(64)
        skT[d * TT + t] = qkv[base + D];
        sv[idx] = qkv[base + 2 * D];
    }
    int len = max(tgt_len[n], 1);
    __syncthreads();
    for (int r = w; r < TT; r += 4) {
        bool ok = (lane < TT) && (lane <= r) && (lane < len);
        float s = -INFINITY;
        if (ok) {
            float dot = 0.f;
#pragma unroll 8
            for (int d = 0; d < HD; ++d) dot += sq[r * HD + d] * skT[d * TT + lane];
            s = dot;
        }
        float mx = wmax(s);
        float e = ok ? __expf(s - mx) : 0.f;
        float sum = wsum(e);
        float att = e / sum;
        float o = 0.f;
#pragma unroll
        for (int k = 0; k < TT; ++k) {
            float a = __shfl(att, k, 64);
            o += a * sv[k * HD + lane];
        }
        size_t oi = (size_t)(r * NB + n) * D + h * HD + lane;
        u16 hv = f2bf(o);
        oh[oi] = hv;
        ol[oi] = f2bf(o - bf2f(hv));
    }
}

// ---------------- residual add (+NP partials) + LayerNorm body ------------
template<int NP, int BIAS>
__device__ void add_ln_body(int bid,
    float* __restrict__ x, const float* __restrict__ r,
    const float* __restrict__ bias2,
    const float* __restrict__ s, const float* __restrict__ b,
    u16* __restrict__ xh, u16* __restrict__ xl)
{
    int row = bid * 4 + (threadIdx.x >> 6);
    int lane = threadIdx.x & 63;
    if (row >= NTOK) return;
    float* xr = x + (size_t)row * D;
    f4 v1 = *(const f4*)(xr + lane * 4);
    f4 v2 = *(const f4*)(xr + 256 + lane * 4);
#pragma unroll
    for (int p = 0; p < NP; ++p) {
        const float* rr = r + (size_t)p * (NTOK * D) + (size_t)row * D;
        v1 += *(const f4*)(rr + lane * 4);
        v2 += *(const f4*)(rr + 256 + lane * 4);
    }
    if (BIAS) {
        v1 += *(const f4*)(bias2 + lane * 4);
        v2 += *(const f4*)(bias2 + 256 + lane * 4);
    }
    float sum = 0.f, sq = 0.f;
#pragma unroll
    for (int j = 0; j < 4; ++j) {
        sum += v1[j] + v2[j];
        sq += v1[j] * v1[j] + v2[j] * v2[j];
    }
    sum = wsum(sum); sq = wsum(sq);
    float mean = sum * (1.f / D);
    float var = sq * (1.f / D) - mean * mean;
    float rstd = rsqrtf(var + 1e-5f);
    f4 o1, o2;
    ushort4 h1, l1, h2, l2;
    u16 th, tl;
#pragma unroll
    for (int j = 0; j < 4; ++j) {
        int c1 = lane * 4 + j, c2 = c1 + 256;
        o1[j] = (v1[j] - mean) * rstd * s[c1] + b[c1];
        o2[j] = (v2[j] - mean) * rstd * s[c2] + b[c2];
    }
    th = f2bf(o1[0]); tl = f2bf(o1[0] - bf2f(th)); h1.x = th; l1.x = tl;
    th = f2bf(o1[1]); tl = f2bf(o1[1] - bf2f(th)); h1.y = th; l1.y = tl;
    th = f2bf(o1[2]); tl = f2bf(o1[2] - bf2f(th)); h1.z = th; l1.z = tl;
    th = f2bf(o1[3]); tl = f2bf(o1[3] - bf2f(th)); h1.w = th; l1.w = tl;
    th = f2bf(o2[0]); tl = f2bf(o2[0] - bf2f(th)); h2.x = th; l2.x = tl;
    th = f2bf(o2[1]); tl = f2bf(o2[1] - bf2f(th)); h2.y = th; l2.y = tl;
    th = f2bf(o2[2]); tl = f2bf(o2[2] - bf2f(th)); h2.z = th; l2.z = tl;
    th = f2bf(o2[3]); tl = f2bf(o2[3] - bf2f(th)); h2.w = th; l2.w = tl;
    *(f4*)(xr + lane * 4) = o1;
    *(f4*)(xr + 256 + lane * 4) = o2;
    *(ushort4*)(xh + (size_t)row * D + lane * 4) = h1;
    *(ushort4*)(xl + (size_t)row * D + lane * 4) = l1;
    *(ushort4*)(xh + (size_t)row * D + 256 + lane * 4) = h2;
    *(ushort4*)(xl + (size_t)row * D + 256 + lane * 4) = l2;
}

// ---------------- fused 6-layer decoder (resident grid, atomic barriers) --
// Stage tile->block maps are XCD-chunked: blocks sharing a weight panel get
// the same (bid & 7) so panel re-reads hit the XCD-local L2 (any bijection
// is correct; the %8 placement assumption only affects locality).
__global__ __launch_bounds__(256, 1) void decoder_coop(
    const u16* __restrict__ Wh, const u16* __restrict__ Wl,
    const float* __restrict__ qkv_b, const float* __restrict__ o_b,
    const float* __restrict__ ln1_s, const float* __restrict__ ln1_b,
    const float* __restrict__ ff1_b, const float* __restrict__ ff2_b,
    const float* __restrict__ ln2_s, const float* __restrict__ ln2_b,
    const float* __restrict__ enc_b, const int* __restrict__ tgt_len,
    float* __restrict__ x, float* __restrict__ qkvb,
    float* __restrict__ part, float* __restrict__ encb,
    u16* __restrict__ xh, u16* __restrict__ xl,
    u16* __restrict__ oh, u16* __restrict__ ol,
    u16* __restrict__ hh, u16* __restrict__ hl,
    const u16* __restrict__ eh, const u16* __restrict__ el,
    unsigned* __restrict__ bar)
{
    __shared__ u16 ls[3][4][2048];   // 48 KiB: 3-deep staging; fp32 for attn
    const int bid = blockIdx.x;
    const int tid = threadIdx.x;

    unsigned xcc;
    asm("s_getreg_b32 %0, hwreg(HW_REG_XCC_ID, 0, 4)" : "=s"(xcc));
    xcc &= 7;
    unsigned* gbar  = bar;            // init counter        [0]
    unsigned* gbar2 = bar + 16;       // sync counter        [16]
    unsigned* xcnt  = bar + 64;       // 8 x stride-32       [64..288)
    unsigned* xarr  = bar + 320;      // 8 x stride-32       [320..544)
    unsigned* xdn   = bar + 576;      // 8 x stride-32       [576..800)

    // init: count blocks per XCD, one contended global barrier (once), then
    // every block reads its XCD's block count and the # of populated XCDs.
    __shared__ unsigned s_nblk, s_nx;
    if (tid == 0) {
        __hip_atomic_fetch_add(&xcnt[xcc * 32], 1u, __ATOMIC_ACQ_REL,
                               __HIP_MEMORY_SCOPE_AGENT);
        __hip_atomic_fetch_add(gbar, 1u, __ATOMIC_ACQ_REL, __HIP_MEMORY_SCOPE_AGENT);
        while (__hip_atomic_load(gbar, __ATOMIC_ACQUIRE,
                                 __HIP_MEMORY_SCOPE_AGENT) < (unsigned)GRID)
            __builtin_amdgcn_s_sleep(2);
        s_nblk = __hip_atomic_load(&xcnt[xcc * 32], __ATOMIC_ACQUIRE,
                                   __HIP_MEMORY_SCOPE_AGENT);
        unsigned nx = 0;
#pragma unroll
        for (int i = 0; i < 8; ++i)
            nx += (__hip_atomic_load(&xcnt[i * 32], __ATOMIC_ACQUIRE,
                                     __HIP_MEMORY_SCOPE_AGENT) != 0u);
        s_nx = nx;
    }
    __syncthreads();
    const unsigned nblk = s_nblk, nx = s_nx;
    unsigned gs = 0;

    const int xg = bid & 7, jg = bid >> 3;

    for (int l = 0; l < NL; ++l) {
        const u16* WqH = Wh + QO + (size_t)l * 786432;
        const u16* WqL = Wl + QO + (size_t)l * 786432;
        const u16* WoH = Wh + OO + (size_t)l * 262144;
        const u16* WoL = Wl + OO + (size_t)l * 262144;
        const u16* W1H = Wh + F1 + (size_t)l * 1048576;
        const u16* W1L = Wl + F1 + (size_t)l * 1048576;
        const u16* W2H = Wh + F2 + (size_t)l * 1048576;
        const u16* W2L = Wl + F2 + (size_t)l * 1048576;

        // S1: qkv projection (120 blocks); layer 0 also runs the enc GEMM
        if (bid < 120) {
            int mt = jg % 5, nt = (jg / 5) * 8 + xg;   // same-nt -> same XCD
            gemm_tile<0>(ls, mt, nt, 0,
                         xh, xl, 512, WqH, WqL, 512,
                         qkv_b + l * 1536, qkvb, nullptr, nullptr,
                         NTOK, 1536, 16);
        } else if (l == 0 && bid < 248) {
            int t = bid - 120;   // 16 row-tiles x 8 col-tiles (nt = t&7 = XCD)
            gemm_tile<0>(ls, t >> 3, t & 7, 0,
                         eh, el, 512, Wh + EW, Wl + EW, 512,
                         enc_b, encb, nullptr, nullptr,
                         TI * NB, 512, 16);
        }
        grid_sync(++gs, xcc, nblk, nx, gbar2, xarr, xdn);

        // S2: attention
        if (bid < NB * NH) attn_body((u16*)ls, bid, qkvb, tgt_len, oh, ol);
        grid_sync(++gs, xcc, nblk, nx, gbar2, xarr, xdn);

        // S3: o-projection, split-K x4 (K=512 -> 4 slices of 128)
        if (bid < 160) {
            int z = jg % 4, mt = jg / 4, nt = xg;
            gemm_tile<1>(ls, mt, nt, z,
                         oh, ol, 512, WoH, WoL, 512,
                         nullptr, part, nullptr, nullptr,
                         NTOK, 512, 4);
        }
        grid_sync(++gs, xcc, nblk, nx, gbar2, xarr, xdn);

        // S4: x = LN(x + sum(part) + o_b)
        if (bid < 66) add_ln_body<4, 1>(bid, x, part, o_b + l * 512,
                                        ln1_s + l * 512, ln1_b + l * 512, xh, xl);
        grid_sync(++gs, xcc, nblk, nx, gbar2, xarr, xdn);

        // S5: ff1 + relu -> bf16 hi/lo
        if (bid < 160) {
            int mt = jg % 5, nt = (jg / 5) * 8 + xg;
            gemm_tile<2>(ls, mt, nt, 0,
                         xh, xl, 512, W1H, W1L, 512,
                         ff1_b + l * 2048, nullptr, hh, hl,
                         NTOK, 2048, 16);
        }
        grid_sync(++gs, xcc, nblk, nx, gbar2, xarr, xdn);

        // S6: ff2, split-K x4 (K=2048 -> 4 slices of 512)
        if (bid < 160) {
            int z = jg % 4, mt = jg / 4, nt = xg;
            gemm_tile<1>(ls, mt, nt, z,
                         hh, hl, 2048, W2H, W2L, 2048,
                         nullptr, part, nullptr, nullptr,
                         NTOK, 512, 16);
        }
        grid_sync(++gs, xcc, nblk, nx, gbar2, xarr, xdn);

        // S7: x = LN(x + sum(part) + ff2_b)
        if (bid < 66) add_ln_body<4, 1>(bid, x, part, ff2_b + l * 512,
                                        ln2_s + l * 512, ln2_b + l * 512, xh, xl);
        if (l < NL - 1) grid_sync(++gs, xcc, nblk, nx, gbar2, xarr, xdn);
    }
}

// ---------------- joiner prep: A = bf16(tanh(enc + x)), B = bf16(out_w) ---
__global__ __launch_bounds__(256) void prep_joiner(
    const float* __restrict__ encb, const float* __restrict__ x,
    u16* __restrict__ Aj, const float* __restrict__ out_w, u16* __restrict__ Bj)
{
    const int bid = blockIdx.x;
    if (bid < 8448) {
        int idx = bid * 256 + threadIdx.x;
        int d8 = (idx & 63) << 3;
        int row = idx >> 6;                              // (n*TI+ti)*TT + t
        int n = row / (TI * TT);
        int rem = row - n * (TI * TT);
        int ti = rem / TT;
        int t = rem - ti * TT;
        const float* pe = encb + (size_t)(ti * NB + n) * D + d8;
        const float* px = x + (size_t)(t * NB + n) * D + d8;
        f4 e0 = *(const f4*)pe, e1 = *(const f4*)(pe + 4);
        f4 x0 = *(const f4*)px, x1 = *(const f4*)(px + 4);
        u16* dst = Aj + (size_t)row * D + d8;
#pragma unroll
        for (int j = 0; j < 4; ++j) {
            dst[j] = f2bf(tanhf(e0[j] + x0[j]));
            dst[4 + j] = f2bf(tanhf(e1[j] + x1[j]));
        }
    } else {
        int idx = (bid - 8448) * 256 + threadIdx.x;      // 2048x512 / 8
        int d8 = (idx & 63) << 3;
        int row = idx >> 6;
        u16* dst = Bj + (size_t)row * D + d8;
        if (row < V) {
            const float* p = out_w + (size_t)row * D + d8;
            f4 a = *(const f4*)p, b = *(const f4*)(p + 4);
#pragma unroll
            for (int j = 0; j < 4; ++j) { dst[j] = f2bf(a[j]); dst[4 + j] = f2bf(b[j]); }
        } else {
#pragma unroll
            for (int j = 0; j < 8; ++j) dst[j] = 0;
        }
    }
}

// ---------------- joiner GEMM: out[MJ x 2000] = Aj * Bj^T (bf16 MFMA) -----
// XCD-chunked remap: each XCD owns 33 A-panels (all 16 n-tiles of each),
// so the A panel is fetched from MALL once per XCD instead of 16x.
// Depth-2 pipelined staging, nontemporal output stores.
__global__ __launch_bounds__(256) void joiner_gemm(
    const u16* __restrict__ Aj, const u16* __restrict__ Bj,
    float* __restrict__ out)
{
    __shared__ u16 lsA[3][128 * 32];
    __shared__ u16 lsB[3][128 * 32];
    const int bid = blockIdx.x;
    const int v = (bid & 7) * 528 + (bid >> 3);   // 4224 = 8 * 528, bijective
    const int mt = v >> 4, nt = v & 15;
    const int tid = threadIdx.x, lane = tid & 63, w = tid >> 6;
    const int wr = (w >> 1) * 64, wc = (w & 1) * 64;
    const int qd = lane >> 4, mm = lane & 15;
    f4 acc[4][4] = {};
    const u16* Abase = Aj + (size_t)mt * 128 * D;
    const u16* Bbase = Bj + (size_t)nt * 128 * D;

    auto stage = [&](int b, int it) {
        int k0 = it * 32;
#pragma unroll
        for (int i = 0; i < 2; ++i) {
            int idx = tid + i * 256;
            int row = idx >> 2, c = idx & 3;
            int chunk = c ^ ((row >> 1) & 3);
            async16(Abase + (size_t)row * D + k0 + chunk * 8, &lsA[b][idx * 8]);
            async16(Bbase + (size_t)row * D + k0 + chunk * 8, &lsB[b][idx * 8]);
        }
    };
    stage(0, 0);
    stage(1, 1);
    for (int it = 0; it < 16; ++it) {
        if (it < 15) asm volatile("s_waitcnt vmcnt(4)" ::: "memory");
        else         asm volatile("s_waitcnt vmcnt(0)" ::: "memory");
        __builtin_amdgcn_s_barrier();
        if (it + 2 < 16) stage((it + 2) % 3, it + 2);
        const int cur = it % 3;
        shortx8 af[4], bf[4];
#pragma unroll
        for (int rt = 0; rt < 4; ++rt) {
            int row = wr + rt * 16 + mm;
            int cpos = qd ^ ((row >> 1) & 3);
            af[rt] = *(const shortx8*)&lsA[cur][row * 32 + cpos * 8];
        }
#pragma unroll
        for (int ct = 0; ct < 4; ++ct) {
            int col = wc + ct * 16 + mm;
            int cpos = qd ^ ((col >> 1) & 3);
            bf[ct] = *(const shortx8*)&lsB[cur][col * 32 + cpos * 8];
        }
#pragma unroll
        for (int rt = 0; rt < 4; ++rt)
#pragma unroll
            for (int ct = 0; ct < 4; ++ct)
                acc[rt][ct] = mfma16(af[rt], bf[ct], acc[rt][ct]);
    }
#pragma unroll
    for (int rt = 0; rt < 4; ++rt)
#pragma unroll
        for (int ct = 0; ct < 4; ++ct)
#pragma unroll
            for (int reg = 0; reg < 4; ++reg) {
                int grow = mt * 128 + wr + rt * 16 + qd * 4 + reg;
                int gcol = nt * 128 + wc + ct * 16 + mm;
                if (gcol < V)
                    __builtin_nontemporal_store(acc[rt][ct][reg],
                                                &out[(size_t)grow * V + gcol]);
            }
}

// --------------------------------------------------------------------------
extern "C" void kernel_launch(void* const* d_in, const int* in_sizes, int n_in,
                              void* d_out, int out_size, void* d_ws, size_t ws_size,
                              hipStream_t stream)
{
    const float* enc_out = (const float*)d_in[0];
    const float* embed_w = (const float*)d_in[1];
    const float* enc_w   = (const float*)d_in[2];
    const float* enc_b   = (const float*)d_in[3];
    const float* qkv_w   = (const float*)d_in[4];
    const float* qkv_b   = (const float*)d_in[5];
    const float* o_w     = (const float*)d_in[6];
    const float* o_b     = (const float*)d_in[7];
    const float* ln1_s   = (const float*)d_in[8];
    const float* ln1_b   = (const float*)d_in[9];
    const float* ff1_w   = (const float*)d_in[10];
    const float* ff1_b   = (const float*)d_in[11];
    const float* ff2_w   = (const float*)d_in[12];
    const float* ff2_b   = (const float*)d_in[13];
    const float* ln2_s   = (const float*)d_in[14];
    const float* ln2_b   = (const float*)d_in[15];
    const float* out_w   = (const float*)d_in[16];
    const int*   tgt_pad = (const int*)d_in[17];
    const int*   tgt_len = (const int*)d_in[18];
    const int*   sos     = (const int*)d_in[19];

    float* ws = (float*)d_ws;
    float* x    = ws;                  // 264x512 = 135168 f
    float* qkvb = ws + 135168;         // 264x1536 = 405504 f
    unsigned* bar = (unsigned*)(ws + 540672);   // 1024 u32 barrier state
    float* part = ws + 675840;         // 4x264x512 = 540672 f
    float* encb = ws + 1216512;        // 1024x512 = 524288 f
    u16* u  = (u16*)(ws + 1740800);
    u16* xh = u;                  u16* xl = xh + 320 * 512;     // padded to 320 rows
    u16* oh = xl + 163840;        u16* ol = oh + 163840;
    u16* hh = ol + 163840;        u16* hl = hh + 320 * 2048;    // 655360 each
    u16* eh = hl + 655360;        u16* el = eh + 524288;        // 1024x512
    u16* Wh = el + 524288;        u16* Wl = Wh + 19136512;
    u16* Aj = Wl + 19136512;      u16* Bj = Aj + (size_t)MJ * D;

    fused_convert<<<19728, 256, 0, stream>>>(
        qkv_w, o_w, ff1_w, ff2_w, enc_w, Wh, Wl,
        enc_out, eh, el, embed_w, tgt_pad, sos, x, xh, xl, bar);

    decoder_coop<<<GRID, 256, 0, stream>>>(
        Wh, Wl, qkv_b, o_b, ln1_s, ln1_b, ff1_b, ff2_b, ln2_s, ln2_b,
        enc_b, tgt_len, x, qkvb, part, encb,
        xh, xl, oh, ol, hh, hl, eh, el, bar);

    prep_joiner<<<8960, 256, 0, stream>>>(encb, x, Aj, out_w, Bj);

    joiner_gemm<<<264 * 16, 256, 0, stream>>>(Aj, Bj, (float*)d_out);
}